// Round 6
// baseline (478.451 us; speedup 1.0000x reference)
//
#include <hip/hip_runtime.h>

typedef __attribute__((ext_vector_type(8))) short short8;
typedef __attribute__((ext_vector_type(4))) float f32x4;

constexpr int L = 1024, C = 256, F = 256;
constexpr int NIMG = 256;          // B*M
constexpr int LOUT = 1022;         // L - K + 1
constexpr long MAXROW = (long)NIMG * L - 1;

__device__ inline unsigned short f2bf(float f) {
  union { float f; unsigned u; } v; v.f = f;
  return (unsigned short)((v.u + 0x7FFFu + ((v.u >> 16) & 1u)) >> 16);  // RNE
}

__device__ inline void g2l16(const unsigned short* g, unsigned short* l) {
  __builtin_amdgcn_global_load_lds(
      (const __attribute__((address_space(1))) unsigned int*)g,
      (__attribute__((address_space(3))) unsigned int*)l, 16, 0, 0);
}

// LDS chunk swizzle: row-major [rows][32 bf16] tiles, 16-B chunks (4/row).
// Quarter-wave reads (16 rows, same chunk col) hit only 2 bank groups ->
// measured 12.6M conflict cycles. XOR row bits 2:1 into the chunk col:
// rows 0..7 then cover all 32 banks; 16 lanes -> 2/bank (free, m136).
__device__ inline int swz(int row, int col) { return col ^ ((row >> 1) & 3); }

// Pre-pass: W (3,256,256) fp32 -> Wt bf16, layout [tile(slab*3+k)][f(256)][chunk]
// with the chunk col PRE-swizzled so the main kernel's linear global_load_lds
// DMA lands data at swizzled LDS slots (rule #21: swizzle source + read).
__global__ void wprep(const float* __restrict__ W, unsigned short* __restrict__ Wt) {
  int tid = blockIdx.x * 256 + threadIdx.x;       // exactly 768*256 threads
  int kc = tid >> 8, f = tid & 255;               // coalesced read of W[tid]
  int k = kc >> 8, c = kc & 255;
  int slab = c >> 5, kp = c & 31;
  int qd = kp >> 3, j = kp & 7;                   // data chunk col, elem
  Wt[(size_t)((((slab * 3 + k) * 256 + f) * 4 + swz(f, qd)) * 8 + j)] = f2bf(W[tid]);
}

// R5 structure (best: 163 us): 512 thr, 128Lx256F block, 64x64 wave tile,
// 2 regions/slab, counted vmcnt, 2 blocks/CU (64 VGPR + 64 acc-AGPR = 128).
// R6 adds the bank-conflict swizzle on As (write+read) and Bs (wprep+read).
__global__ __launch_bounds__(512, 4) void conv_mfma(
    const float* __restrict__ x, const unsigned short* __restrict__ Wt,
    const float* __restrict__ bias, float* __restrict__ y)
{
  __shared__ __align__(16) unsigned short As[2][520 * 8];   // 2 x 8320 B (130 rows x 32 bf16)
  __shared__ __align__(16) unsigned short Bs[3][512 * 16];  // 3 x 16384 B (256 f x 32 bf16)

  const int bid = blockIdx.x;       // 2048 blocks
  const int mt  = bid & 7;          // 8 m-tiles of 128 rows over Lout=1022
  const int img = bid >> 3;         // 256 images
  const int l0  = mt * 128;

  const int tid  = threadIdx.x;
  const int lane = tid & 63;
  const int wv   = tid >> 6;        // 8 waves: 2(M) x 4(F); wave tile 64 x 64
  const int wr   = wv >> 2;
  const int wc   = wv & 3;
  const int lr   = lane & 15;
  const int quad = lane >> 4;

  f32x4 acc[4][4] = {};
  float4 av[2];                     // A chunk tid (2 dwordx4 loads/wave)
  float4 avt[2];                    // tail chunks 512..519 (wave 0 only, +2 loads)

  const long gb = (long)img * L + l0;

  auto issue_A = [&](int slab) {    // global -> regs, rows 0..129 of slab (fp32)
    const int cb = slab * 32;
    long g0 = gb + (tid >> 2); if (g0 > MAXROW) g0 = MAXROW;   // clamped rows feed
    const float* p0 = x + g0 * C + cb + (tid & 3) * 8;         // only masked outputs
    av[0] = *(const float4*)p0; av[1] = *(const float4*)(p0 + 4);
    if (tid < 8) {
      long g2 = gb + 128 + (tid >> 2); if (g2 > MAXROW) g2 = MAXROW;
      const float* p2 = x + g2 * C + cb + (tid & 3) * 8;
      avt[0] = *(const float4*)p2; avt[1] = *(const float4*)(p2 + 4);
    }
  };

  auto pack8 = [&](float4 a, float4 b) {
    short8 r;
    r[0] = (short)f2bf(a.x); r[1] = (short)f2bf(a.y);
    r[2] = (short)f2bf(a.z); r[3] = (short)f2bf(a.w);
    r[4] = (short)f2bf(b.x); r[5] = (short)f2bf(b.y);
    r[6] = (short)f2bf(b.z); r[7] = (short)f2bf(b.w);
    return r;
  };

  auto write_A = [&](int ab2) {     // chunk c=(row,qd) -> slot (row, swz): each
    {                               // 16-B slot written exactly once, balanced
      const int row = tid >> 2, qd = tid & 3;
      *(short8*)(As[ab2] + (size_t)(row * 4 + swz(row, qd)) * 8) = pack8(av[0], av[1]);
    }
    if (tid < 8) {
      const int c = 512 + tid, row = c >> 2, qd = c & 3;
      *(short8*)(As[ab2] + (size_t)(row * 4 + swz(row, qd)) * 8) = pack8(avt[0], avt[1]);
    }
  };

  auto stage_B = [&](int tile, int bb) {  // 16 KB contiguous, 2 g2l16/thread
    const unsigned short* bsrc = Wt + (size_t)tile * 8192;   // pre-swizzled in wprep
    g2l16(bsrc + (size_t)tid * 8,         Bs[bb] + (size_t)tid * 8);
    g2l16(bsrc + (size_t)(tid + 512) * 8, Bs[bb] + (size_t)(tid + 512) * 8);
  };

  auto read_af = [&](int ab2, int k, int mi) {
    const int row = wr * 64 + mi * 16 + lr + k;
    return *(const short8*)(As[ab2] + (size_t)(row * 4 + swz(row, quad)) * 8);
  };
  auto read_bf = [&](int kbuf, int ni) {
    const int frow = wc * 64 + ni * 16 + lr;
    return *(const short8*)(Bs[kbuf] + (size_t)(frow * 4 + swz(frow, quad)) * 8);
  };

#define BAR  __builtin_amdgcn_s_barrier()
#define SBAR __builtin_amdgcn_sched_barrier(0)

  // ---- prologue: B0, B1, av(0) issued; write_A drains av (compiler wait);
  // R0(0)'s top wait (vmcnt0+lgkm0) finishes the drain before the barrier.
  stage_B(0, 0);
  stage_B(1, 1);
  issue_A(0);
  write_A(0);

  for (int s = 0; s < 8; ++s) {
    const int ab = s & 1;

    // ======== R0(s): taps 0,1 ========
    // top: pending = R1(s-1)'s 4 stage loads (or prologue) -> drain all;
    // lgkm0 publishes write_A(ab) from R1(s-1).
    asm volatile("s_waitcnt vmcnt(0) lgkmcnt(0)" ::: "memory");
    BAR; SBAR;

    stage_B(3 * s + 2, 2);          // Bs[2] not read in R0; consumed in R1(s)
    if (s < 7) issue_A(s + 1);      // av after stage (FIFO: R1-top keeps av)

#pragma unroll
    for (int tap = 0; tap < 2; ++tap) {
      short8 af[4], bf[4];
#pragma unroll
      for (int mi = 0; mi < 4; ++mi) af[mi] = read_af(ab, tap, mi);
#pragma unroll
      for (int ni = 0; ni < 4; ++ni) bf[ni] = read_bf(tap, ni);  // tile 3s+tap
      __builtin_amdgcn_s_setprio(1);
#pragma unroll
      for (int mi = 0; mi < 4; ++mi)
#pragma unroll
        for (int ni = 0; ni < 4; ++ni)
          acc[mi][ni] = __builtin_amdgcn_mfma_f32_16x16x32_bf16(
              af[mi], bf[ni], acc[mi][ni], 0, 0, 0);
      __builtin_amdgcn_s_setprio(0);
    }

    // ======== R1(s): tap 2 ========
    // top: pending (s<7) = [tile 3s+2 (2), av (2)] -> vmcnt(2) drains the tile,
    // keeps av in flight (wave0's avt: same count is stricter, safe).
    // s==7: no av -> vmcnt(0).
    if (s < 7) asm volatile("s_waitcnt vmcnt(2)" ::: "memory");
    else       asm volatile("s_waitcnt vmcnt(0)" ::: "memory");
    BAR; SBAR;

    if (s < 7) {                    // Bs[0]/Bs[1] fully consumed in R0(s)
      stage_B(3 * s + 3, 0);
      stage_B(3 * s + 4, 1);
    }

    {
      short8 af[4], bf[4];
#pragma unroll
      for (int mi = 0; mi < 4; ++mi) af[mi] = read_af(ab, 2, mi);
#pragma unroll
      for (int ni = 0; ni < 4; ++ni) bf[ni] = read_bf(2, ni);    // tile 3s+2
      __builtin_amdgcn_s_setprio(1);
#pragma unroll
      for (int mi = 0; mi < 4; ++mi)
#pragma unroll
        for (int ni = 0; ni < 4; ++ni)
          acc[mi][ni] = __builtin_amdgcn_mfma_f32_16x16x32_bf16(
              af[mi], bf[ni], acc[mi][ni], 0, 0, 0);
      __builtin_amdgcn_s_setprio(0);
    }

    if (s < 7) write_A(ab ^ 1);     // after MFMAs: implicit av-wait off the
                                    // critical path; published at next R0-top
  }

  // Epilogue: C/D layout col=lane&15, row=quad*4+reg (m89/m91-verified)
  float bv[4];
#pragma unroll
  for (int ni = 0; ni < 4; ++ni)
    bv[ni] = bias[wc * 64 + ni * 16 + lr];

#pragma unroll
  for (int mi = 0; mi < 4; ++mi) {
#pragma unroll
    for (int r = 0; r < 4; ++r) {
      const int lrow = l0 + wr * 64 + mi * 16 + quad * 4 + r;
      if (lrow < LOUT) {
        float* yp = y + ((size_t)img * LOUT + lrow) * F + wc * 64 + lr;
#pragma unroll
        for (int ni = 0; ni < 4; ++ni)
          yp[ni * 16] = acc[mi][ni][r] + bv[ni];
      }
    }
  }
#undef BAR
#undef SBAR
}

extern "C" void kernel_launch(void* const* d_in, const int* in_sizes, int n_in,
                              void* d_out, int out_size, void* d_ws, size_t ws_size,
                              hipStream_t stream) {
  const float* x = (const float*)d_in[0];   // (8,32,1024,256) fp32
  const float* W = (const float*)d_in[1];   // (3,256,256) fp32
  const float* b = (const float*)d_in[2];   // (256,) fp32
  float* y = (float*)d_out;                 // (8,32,1022,256) fp32
  unsigned short* Wt = (unsigned short*)d_ws;  // 3*256*256*2 = 393,216 B

  wprep<<<768, 256, 0, stream>>>(W, Wt);
  conv_mfma<<<NIMG * 8, 512, 0, stream>>>(x, Wt, b, y);
}